// Round 1
// baseline (1296.457 us; speedup 1.0000x reference)
//
#include <hip/hip_runtime.h>

// LSTM, B=512 x T=1024, H=100, input_size=1.
// R5 theory: VGPR_Count=56 in R4's counters proves the asm-pinned weight set
// was SPILLED TO SCRATCH (52 pinned floats can't live in 56 regs) -> every
// timestep re-loads 208 B/thread of W_hh from scratch (~2600 cyc/step/CU),
// which matches the measured 2900 cyc/step vs ~1000 cyc/step VALU floor.
// Fixes:
//   (a) amdgpu_waves_per_eu(4,4) + launch_bounds(896,4): pins the allocator
//       to a 128-VGPR budget (14-wave block = 4,4,3,3 waves/SIMD) instead of
//       chasing 8-wave occupancy with a 64-reg cap.
//   (b) sched_barrier(0) every 4 unrolled dot-iterations: caps in-flight
//       ds_read_b128 at 8 (32 regs) so peak pressure ~= 52w + 32h + 8acc +
//       ~18 misc ~= 110 < 128 (the prior "spill at 128" was scheduler
//       hoisting all 26 h-loads, peak ~180).
//   (c) x-projection + gate activations moved into Phase A (wave-parallel,
//       throughput-hidden) -> Phase B shrinks to {4 LDS reads, c-update,
//       tanh, h-write}, shortening the all-waves-idle serial tail and
//       freeing Phase-B's 8 constant regs.
//
// Structure (unchanged): block = 896 (14 waves), jobs 0..799 = 400 rows x 2
// halves (even lane k in [0,52), odd lane k in [48,100), first 4 zeroed);
// partials combine via __shfl_xor(p,1). Wave 13 = output projection.
// Grid = 256 blocks (2 batches/block) -> 1 block/CU.

#define HID   100
#define TLEN  1024
#define BLOCK 896
#define NJOB  800

__global__ __launch_bounds__(BLOCK, 4)
__attribute__((amdgpu_waves_per_eu(4, 4)))
void lstm_split(
    const float* __restrict__ input,   // [B, T]
    const float* __restrict__ W_ih,    // [4H]
    const float* __restrict__ W_hh,    // [4H, H]
    const float* __restrict__ b_ih,    // [4H]
    const float* __restrict__ b_hh,    // [4H]
    const float* __restrict__ W_out,   // [H]
    const float* __restrict__ b_out,   // [1]
    float* __restrict__ out)           // [B, T]
{
    const int b0  = blockIdx.x * 2;
    const int tid = threadIdx.x;

    __shared__ float4 h0_4[26];        // h batch0: 100 floats + pad
    __shared__ float4 h1_4[26];        // h batch1
    __shared__ float  g0_s[400];       // ACTIVATED gates, batch0
    __shared__ float  g1_s[400];
    __shared__ float  in0_s[TLEN];
    __shared__ float  in1_s[TLEN];

    float* h0_s = (float*)h0_4;
    float* h1_s = (float*)h1_4;

    // Stage both input rows (8 KB), coalesced.
    for (int i = tid; i < TLEN; i += BLOCK) {
        in0_s[i] = input[(b0 + 0) * TLEN + i];
        in1_s[i] = input[(b0 + 1) * TLEN + i];
    }

    // ---- Phase-A role: thread = (row, half)
    const int row  = (tid < NJOB ? tid : 0) >> 1;   // 0..399
    const int half = tid & 1;
    float4 w[13];                                   // 52 weight regs
    {
        const float4* wp = (const float4*)(W_hh + row * HID + half * 48);
        #pragma unroll
        for (int cc = 0; cc < 13; ++cc) {
            float4 v = wp[cc];
            asm volatile("" : "+v"(v.x), "+v"(v.y), "+v"(v.z), "+v"(v.w));
            w[cc] = v;
        }
        if (half) { w[0].x = 0.f; w[0].y = 0.f; w[0].z = 0.f; w[0].w = 0.f; }
    }
    // Per-row input projection + activation constants.
    //   rows [0,100)=i sigmoid, [100,200)=f sigmoid, [200,300)=g tanh,
    //   [300,400)=o sigmoid.  tanh(u) = 2*sigm(2u)-1.
    const float wi_r = W_ih[row];
    const float bi_r = b_ih[row] + b_hh[row];
    const bool  is_g = (row >= 200) && (row < 300);
    const float gm   = is_g ? 2.f : 1.f;    // input multiplier (and out scale)
    const float gb   = is_g ? -1.f : 0.f;   // out offset

    // ---- Phase-B role: tid<200 -> (batch = tid/100, unit j = tid%100)
    const int pbj = (tid < 200) ? (tid % 100) : 0;

    // ---- Phase-C role: wave 13 (tid 832..895)
    const int cl = tid - 832;
    float wo0 = 0.f, wo1 = 0.f, bo = 0.f;
    if (cl >= 0) {
        wo0 = W_out[cl & 63];
        wo1 = ((cl & 63) < HID - 64) ? W_out[64 + (cl & 63)] : 0.f;
        bo  = b_out[0];
    }

    float c = 0.f;                     // cell state (Phase-B threads)
    if (tid < 104) { h0_s[tid] = 0.f; h1_s[tid] = 0.f; }
    __syncthreads();

    #pragma unroll 1
    for (int t = 0; t < TLEN; ++t) {
        // ---- Phase A: half-row dots + x-proj + activation, both batches
        if (tid < NJOB) {
            const float4* h0w = ((const float4*)h0_4) + half * 12;  // +48 floats
            const float4* h1w = ((const float4*)h1_4) + half * 12;
            float a0 = 0.f, a1 = 0.f, a2 = 0.f, a3 = 0.f;
            float d0 = 0.f, d1 = 0.f, d2 = 0.f, d3 = 0.f;
            #pragma unroll
            for (int cc = 0; cc < 13; ++cc) {
                float4 ha = h0w[cc];       // 2 addrs/wave -> broadcast
                float4 hb = h1w[cc];
                float4 wk = w[cc];
                a0 = fmaf(ha.x, wk.x, a0);
                a1 = fmaf(ha.y, wk.y, a1);
                a2 = fmaf(ha.z, wk.z, a2);
                a3 = fmaf(ha.w, wk.w, a3);
                d0 = fmaf(hb.x, wk.x, d0);
                d1 = fmaf(hb.y, wk.y, d1);
                d2 = fmaf(hb.z, wk.z, d2);
                d3 = fmaf(hb.w, wk.w, d3);
                // cap in-flight ds_reads: peak pressure must stay < 128
                if ((cc & 3) == 3) __builtin_amdgcn_sched_barrier(0);
            }
            float p0 = (a0 + a1) + (a2 + a3);
            float p1 = (d0 + d1) + (d2 + d3);
            p0 += __shfl_xor(p0, 1, 64);   // combine the two half-rows (DPP)
            p1 += __shfl_xor(p1, 1, 64);
            // x-projection + activation (both lanes compute; even lane stores)
            float x0 = in0_s[t], x1 = in1_s[t];
            float u0 = fmaf(x0, wi_r, bi_r) + p0;
            float u1 = fmaf(x1, wi_r, bi_r) + p1;
            float v0 = __builtin_amdgcn_rcpf(1.f + __expf(-gm * u0));
            float v1 = __builtin_amdgcn_rcpf(1.f + __expf(-gm * u1));
            float r0 = fmaf(gm, v0, gb);   // sigm: v ; tanh: 2v-1
            float r1 = fmaf(gm, v1, gb);
            if (!half) { g0_s[row] = r0; g1_s[row] = r1; }
        }
        __syncthreads();

        // ---- Phase B: cell update only (200 threads: 100 per batch)
        if (tid < 200) {
            const float* gs = (tid < 100) ? g0_s : g1_s;
            float*       hs = (tid < 100) ? h0_s : h1_s;
            float is = gs[pbj];
            float fs = gs[100 + pbj];
            float gt = gs[200 + pbj];
            float os = gs[300 + pbj];
            c = fmaf(fs, c, is * gt);
            float th = 1.f - 2.f * __builtin_amdgcn_rcpf(__expf(2.f * c) + 1.f);
            hs[pbj] = os * th;
        }
        __syncthreads();

        // ---- Phase C: out[b, t] = dot(h, W_out) + b_out  (wave 13)
        if (cl >= 0) {
            float p = h0_s[cl] * wo0;
            float q = h1_s[cl] * wo0;
            if (cl < HID - 64) {
                p = fmaf(h0_s[64 + cl], wo1, p);
                q = fmaf(h1_s[64 + cl], wo1, q);
            }
            #pragma unroll
            for (int off = 32; off > 0; off >>= 1) {
                p += __shfl_down(p, off);
                q += __shfl_down(q, off);
            }
            if (cl == 0) {
                out[(b0 + 0) * TLEN + t] = p + bo;
                out[(b0 + 1) * TLEN + t] = q + bo;
            }
        }
        // No barrier: Phase C / next Phase A only READ h; the next write to h
        // (Phase B of t+1) is behind the next barrier, which wave 13 also hits.
    }
}

extern "C" void kernel_launch(void* const* d_in, const int* in_sizes, int n_in,
                              void* d_out, int out_size, void* d_ws, size_t ws_size,
                              hipStream_t stream) {
    const float* input = (const float*)d_in[0];
    const float* W_ih  = (const float*)d_in[1];
    const float* W_hh  = (const float*)d_in[2];
    const float* b_ih  = (const float*)d_in[3];
    const float* b_hh  = (const float*)d_in[4];
    const float* W_out = (const float*)d_in[5];
    const float* b_out = (const float*)d_in[6];
    float* out = (float*)d_out;

    const int B = in_sizes[0] / TLEN;  // 512
    lstm_split<<<B / 2, BLOCK, 0, stream>>>(input, W_ih, W_hh, b_ih, b_hh,
                                            W_out, b_out, out);
}

// Round 2
// 1275.452 us; speedup vs baseline: 1.0165x; 1.0165x over previous
//
#include <hip/hip_runtime.h>

// LSTM, B=512 x T=1024, H=100, input_size=1.
// R6: VGPR_Count=60 in R5 proves weights STILL spill to scratch. Diagnosis:
// with BLOCK=896 (14 waves = 3.5 waves/SIMD), "min 4 waves/EU" is only
// satisfiable with 2 workgroups/CU = 7 waves/SIMD -> VGPR cap 512/7 = 73 ->
// granule 64 -> 60 alloc + spill. Scratch reload traffic (52 floats x 896
// thr = 186 KB/CU/step through L2 at ~56 B/cyc) = ~3300 cyc/step = measured.
// Fix: BLOCK=1024 = EXACTLY 4 waves/SIMD from one workgroup, so
// launch_bounds(1024,4) + waves_per_eu(4,4) is self-consistent: 1 block/CU,
// VGPR budget 512/4 = 128. Peak pressure ~107 (52 w + 32 in-flight h + 8 acc
// + misc, sched_barrier-capped) fits under 128 -> weights register-resident.
//
// Structure: jobs 0..799 = 400 rows x 2 halves (even lane k in [0,52), odd
// lane k in [48,100), first 4 zeroed); partials combine via __shfl_xor(p,1).
// Phase B = tid<200 (cell pointwise). Phase C = wave 15 (output projection).
// Waves 13,14 idle at barriers (cheap). Grid = 256 blocks (2 batches each).

#define HID   100
#define TLEN  1024
#define BLOCK 1024
#define NJOB  800

__global__ __launch_bounds__(BLOCK, 4)
__attribute__((amdgpu_waves_per_eu(4, 4)))
void lstm_split(
    const float* __restrict__ input,   // [B, T]
    const float* __restrict__ W_ih,    // [4H]
    const float* __restrict__ W_hh,    // [4H, H]
    const float* __restrict__ b_ih,    // [4H]
    const float* __restrict__ b_hh,    // [4H]
    const float* __restrict__ W_out,   // [H]
    const float* __restrict__ b_out,   // [1]
    float* __restrict__ out)           // [B, T]
{
    const int b0  = blockIdx.x * 2;
    const int tid = threadIdx.x;

    __shared__ float4 h0_4[26];        // h batch0: 100 floats + pad
    __shared__ float4 h1_4[26];        // h batch1
    __shared__ float  g0_s[400];       // ACTIVATED gates, batch0
    __shared__ float  g1_s[400];
    __shared__ float  in0_s[TLEN];
    __shared__ float  in1_s[TLEN];

    float* h0_s = (float*)h0_4;
    float* h1_s = (float*)h1_4;

    // Stage both input rows (8 KB), coalesced.
    for (int i = tid; i < TLEN; i += BLOCK) {
        in0_s[i] = input[(b0 + 0) * TLEN + i];
        in1_s[i] = input[(b0 + 1) * TLEN + i];
    }

    // ---- Phase-A role: thread = (row, half)
    const int row  = (tid < NJOB ? tid : 0) >> 1;   // 0..399
    const int half = tid & 1;
    float4 w[13];                                   // 52 weight regs
    {
        const float4* wp = (const float4*)(W_hh + row * HID + half * 48);
        #pragma unroll
        for (int cc = 0; cc < 13; ++cc) {
            float4 v = wp[cc];
            asm volatile("" : "+v"(v.x), "+v"(v.y), "+v"(v.z), "+v"(v.w));
            w[cc] = v;
        }
        if (half) { w[0].x = 0.f; w[0].y = 0.f; w[0].z = 0.f; w[0].w = 0.f; }
    }
    // Per-row input projection + activation constants.
    //   rows [0,100)=i sigmoid, [100,200)=f sigmoid, [200,300)=g tanh,
    //   [300,400)=o sigmoid.  tanh(u) = 2*sigm(2u)-1.
    const float wi_r = W_ih[row];
    const float bi_r = b_ih[row] + b_hh[row];
    const bool  is_g = (row >= 200) && (row < 300);
    const float gm   = is_g ? 2.f : 1.f;    // input multiplier (and out scale)
    const float gb   = is_g ? -1.f : 0.f;   // out offset

    // ---- Phase-B role: tid<200 -> (batch = tid/100, unit j = tid%100)
    const int pbj = (tid < 200) ? (tid % 100) : 0;

    // ---- Phase-C role: wave 15 (tid 960..1023)
    const int cl = tid - (BLOCK - 64);
    float wo0 = 0.f, wo1 = 0.f, bo = 0.f;
    if (cl >= 0) {
        wo0 = W_out[cl & 63];
        wo1 = ((cl & 63) < HID - 64) ? W_out[64 + (cl & 63)] : 0.f;
        bo  = b_out[0];
    }

    float c = 0.f;                     // cell state (Phase-B threads)
    if (tid < 104) { h0_s[tid] = 0.f; h1_s[tid] = 0.f; }
    __syncthreads();

    #pragma unroll 1
    for (int t = 0; t < TLEN; ++t) {
        // ---- Phase A: half-row dots + x-proj + activation, both batches
        if (tid < NJOB) {
            const float4* h0w = ((const float4*)h0_4) + half * 12;  // +48 floats
            const float4* h1w = ((const float4*)h1_4) + half * 12;
            float a0 = 0.f, a1 = 0.f, a2 = 0.f, a3 = 0.f;
            float d0 = 0.f, d1 = 0.f, d2 = 0.f, d3 = 0.f;
            #pragma unroll
            for (int cc = 0; cc < 13; ++cc) {
                float4 ha = h0w[cc];       // 2 addrs/wave -> broadcast
                float4 hb = h1w[cc];
                float4 wk = w[cc];
                a0 = fmaf(ha.x, wk.x, a0);
                a1 = fmaf(ha.y, wk.y, a1);
                a2 = fmaf(ha.z, wk.z, a2);
                a3 = fmaf(ha.w, wk.w, a3);
                d0 = fmaf(hb.x, wk.x, d0);
                d1 = fmaf(hb.y, wk.y, d1);
                d2 = fmaf(hb.z, wk.z, d2);
                d3 = fmaf(hb.w, wk.w, d3);
                // cap in-flight ds_reads: peak pressure must stay < 128
                if ((cc & 3) == 3) __builtin_amdgcn_sched_barrier(0);
            }
            float p0 = (a0 + a1) + (a2 + a3);
            float p1 = (d0 + d1) + (d2 + d3);
            p0 += __shfl_xor(p0, 1, 64);   // combine the two half-rows (DPP)
            p1 += __shfl_xor(p1, 1, 64);
            // x-projection + activation (both lanes compute; even lane stores)
            float x0 = in0_s[t], x1 = in1_s[t];
            float u0 = fmaf(x0, wi_r, bi_r) + p0;
            float u1 = fmaf(x1, wi_r, bi_r) + p1;
            float v0 = __builtin_amdgcn_rcpf(1.f + __expf(-gm * u0));
            float v1 = __builtin_amdgcn_rcpf(1.f + __expf(-gm * u1));
            float r0 = fmaf(gm, v0, gb);   // sigm: v ; tanh: 2v-1
            float r1 = fmaf(gm, v1, gb);
            if (!half) { g0_s[row] = r0; g1_s[row] = r1; }
        }
        __syncthreads();

        // ---- Phase B: cell update only (200 threads: 100 per batch)
        if (tid < 200) {
            const float* gs = (tid < 100) ? g0_s : g1_s;
            float*       hs = (tid < 100) ? h0_s : h1_s;
            float is = gs[pbj];
            float fs = gs[100 + pbj];
            float gt = gs[200 + pbj];
            float os = gs[300 + pbj];
            c = fmaf(fs, c, is * gt);
            float th = 1.f - 2.f * __builtin_amdgcn_rcpf(__expf(2.f * c) + 1.f);
            hs[pbj] = os * th;
        }
        __syncthreads();

        // ---- Phase C: out[b, t] = dot(h, W_out) + b_out  (wave 15)
        if (cl >= 0) {
            float p = h0_s[cl] * wo0;
            float q = h1_s[cl] * wo0;
            if (cl < HID - 64) {
                p = fmaf(h0_s[64 + cl], wo1, p);
                q = fmaf(h1_s[64 + cl], wo1, q);
            }
            #pragma unroll
            for (int off = 32; off > 0; off >>= 1) {
                p += __shfl_down(p, off);
                q += __shfl_down(q, off);
            }
            if (cl == 0) {
                out[(b0 + 0) * TLEN + t] = p + bo;
                out[(b0 + 1) * TLEN + t] = q + bo;
            }
        }
        // No barrier: Phase C / next Phase A only READ h; the next write to h
        // (Phase B of t+1) is behind the next barrier, which wave 15 also hits.
    }
}

extern "C" void kernel_launch(void* const* d_in, const int* in_sizes, int n_in,
                              void* d_out, int out_size, void* d_ws, size_t ws_size,
                              hipStream_t stream) {
    const float* input = (const float*)d_in[0];
    const float* W_ih  = (const float*)d_in[1];
    const float* W_hh  = (const float*)d_in[2];
    const float* b_ih  = (const float*)d_in[3];
    const float* b_hh  = (const float*)d_in[4];
    const float* W_out = (const float*)d_in[5];
    const float* b_out = (const float*)d_in[6];
    float* out = (float*)d_out;

    const int B = in_sizes[0] / TLEN;  // 512
    lstm_split<<<B / 2, BLOCK, 0, stream>>>(input, W_ih, W_hh, b_ih, b_hh,
                                            W_out, b_out, out);
}